// Round 1
// baseline (19882.088 us; speedup 1.0000x reference)
//
#include <hip/hip_runtime.h>
#include <stdint.h>
#include <stdio.h>

// ---------------------------------------------------------------------------
// DilatedSparseRnnStack: persistent-cluster RNN.
// 8 clusters (128 batch rows each) x 32 WGs (8 SS-columns each, weights in LDS).
// Phase = (t, layer): MFMA gates -> elementwise cell -> publish whole -> barrier.
// ---------------------------------------------------------------------------

typedef __attribute__((ext_vector_type(8))) short short8;
typedef __attribute__((ext_vector_type(4))) float f32x4;

#define DEVINL static __device__ __forceinline__

constexpr int TT = 256, BBATCH = 1024, INW = 64, HSW = 128, OSW = 128, NO = 8;
constexpr int ROWS = 128;                 // batch rows per cluster

constexpr int KLa[4]   = {320, 384, 448, 384};
constexpr int DILa[4]  = {1, 3, 6, 12};
constexpr int PERa[4]  = {2, 4, 7, 13};   // h ring period = dil+1
constexpr int LDWa[4]  = {328, 392, 456, 392};            // padded LDS strides
constexpr int WOFFa[4] = {0, 10496, 23040, 37632};        // ushort offsets

constexpr int GSTRIDE = 36;
constexpr int GATES_B = 50176 * 2;                 // 100,352
constexpr int BIAS_B  = GATES_B + 128 * GSTRIDE * 4;   // 118,784
constexpr int WOUT_B  = BIAS_B + 128 * 4;              // 119,296
constexpr int WSTR    = 129;                           // wout pad (bank-conflict-free)
constexpr int BOUT_B  = WOUT_B + 8 * WSTR * 4;         // 123,424
constexpr int LDS_BYTES = BOUT_B + 32;                 // 123,456

// workspace layout (bytes)
constexpr size_t WSBASE    = 4096;                       // barrier counters first
constexpr size_t BH_OFF[4] = {0, 65536, 196608, 425984}; // h rings (P_l slots of 128x128 bf16)
constexpr size_t OUTB_OFF  = 851968;                     // 4 x 128x128 bf16
constexpr size_t CB_OFF    = 983040;                     // C rings, per (layer, wg)
constexpr size_t CB_L[4]   = {0, 131072, 524288, 1310720};
constexpr size_t CLSZ      = 3866624;
constexpr size_t WS_NEED   = WSBASE + 8 * CLSZ;          // ~29.5 MB

__host__ __device__ constexpr int seg_type(int L, int k) {
  // 0 = x (fp32), 1 = prev-layer out, 2 = prevH, 3 = dH
  if (L == 0) return k < 64 ? 0 : (k < 192 ? 2 : 3);
  if (L == 1) return k < 128 ? 1 : (k < 256 ? 2 : 3);
  if (L == 2) return k < 128 ? 1 : (k < 192 ? 0 : (k < 320 ? 2 : 3));
  return k < 128 ? 1 : (k < 256 ? 2 : 3);
}
__host__ __device__ constexpr int seg_start(int L, int k) {
  if (L == 0) return k < 64 ? 0 : (k < 192 ? 64 : 192);
  if (L == 1) return k < 128 ? 0 : (k < 256 ? 128 : 256);
  if (L == 2) return k < 128 ? 0 : (k < 192 ? 128 : (k < 320 ? 192 : 320));
  return k < 128 ? 0 : (k < 256 ? 128 : 256);
}

template <int N> struct IC { static constexpr int value = N; };

DEVINL unsigned short f2bf(float f) {        // RNE fp32 -> bf16
  union { float f; uint32_t u; } v; v.f = f;
  return (unsigned short)((v.u + 0x7FFFu + ((v.u >> 16) & 1u)) >> 16);
}
DEVINL float bf2f(unsigned short h) {
  union { uint32_t u; float f; } v; v.u = ((uint32_t)h) << 16;
  return v.f;
}
DEVINL float sigm(float x)  { return 1.0f / (1.0f + __expf(-x)); }
DEVINL float tanh_(float x) { return 1.0f - 2.0f / (__expf(2.0f * x) + 1.0f); }

DEVINL short8 zero_s8() { short8 v; for (int i = 0; i < 8; i++) v[i] = 0; return v; }
DEVINL f32x4  zero_f4() { f32x4  v; for (int i = 0; i < 4; i++) v[i] = 0.f; return v; }

DEVINL f32x4 mfma16(short8 a, short8 b, f32x4 c) {
  return __builtin_amdgcn_mfma_f32_16x16x32_bf16(a, b, c, 0, 0, 0);
}

DEVINL short8 ld8f(const float* p) {         // 8 fp32 -> bf16x8 fragment
  const f32x4 u0 = *(const f32x4*)p;
  const f32x4 u1 = *(const f32x4*)(p + 4);
  short8 r;
  r[0] = (short)f2bf(u0[0]); r[1] = (short)f2bf(u0[1]);
  r[2] = (short)f2bf(u0[2]); r[3] = (short)f2bf(u0[3]);
  r[4] = (short)f2bf(u1[0]); r[5] = (short)f2bf(u1[1]);
  r[6] = (short)f2bf(u1[2]); r[7] = (short)f2bf(u1[3]);
  return r;
}

// Device-scope cluster barrier: all prior global writes of all 32 WGs become
// visible (release via __threadfence + wbl2, acquire via __threadfence + inv).
DEVINL void cluster_barrier(unsigned* ctr, unsigned target) {
  __syncthreads();                 // drains this WG's stores (vmcnt 0 before s_barrier)
  if (threadIdx.x == 0) {
    __threadfence();               // release: write back dirty L2 to coherent point
    __hip_atomic_fetch_add(ctr, 1u, __ATOMIC_RELAXED, __HIP_MEMORY_SCOPE_AGENT);
    while (__hip_atomic_load(ctr, __ATOMIC_RELAXED, __HIP_MEMORY_SCOPE_AGENT) < target)
      __builtin_amdgcn_s_sleep(1);
    __threadfence();               // acquire: invalidate L1/L2 so reads are fresh
  }
  __syncthreads();
}

__global__ void __launch_bounds__(256, 1)
rnn_stack_kernel(const float* __restrict__ x,
                 const float* __restrict__ W0, const float* __restrict__ b0,
                 const float* __restrict__ W1, const float* __restrict__ b1,
                 const float* __restrict__ W2, const float* __restrict__ b2,
                 const float* __restrict__ W3, const float* __restrict__ b3,
                 const float* __restrict__ Wout, const float* __restrict__ bout,
                 float* __restrict__ yout, char* __restrict__ ws)
{
  extern __shared__ char smem[];
  unsigned short* wlds = (unsigned short*)smem;
  float* gates = (float*)(smem + GATES_B);
  float* biasl = (float*)(smem + BIAS_B);
  float* woutl = (float*)(smem + WOUT_B);
  float* boutl = (float*)(smem + BOUT_B);

  const int bid = blockIdx.x;
  const int c = bid & 7;           // cluster (XCD-locality heuristic: round-robin dispatch)
  const int g = bid >> 3;          // column-group 0..31 (owns SS cols g*8..g*8+7)
  const int tid = threadIdx.x;

  unsigned* ctr = (unsigned*)(ws + (size_t)c * 256);
  char* cb = ws + WSBASE + (size_t)c * CLSZ;
  unsigned short* bufH[4];
  unsigned short* outb[4];
  float* bufC[4];
#pragma unroll
  for (int l = 0; l < 4; l++) {
    bufH[l] = (unsigned short*)(cb + BH_OFF[l]);
    outb[l] = (unsigned short*)(cb + OUTB_OFF + (size_t)l * ROWS * OSW * 2);
    bufC[l] = (float*)(cb + CB_OFF + CB_L[l] +
                       (size_t)g * ((size_t)DILa[l] * ROWS * 8 * 4));
  }

  // ---- startup: weight/bias slices -> LDS (bf16) ----
  {
    const float* Wsrc[4] = {W0, W1, W2, W3};
    const float* bsrc[4] = {b0, b1, b2, b3};
    for (int l = 0; l < 4; l++) {
      const int K = KLa[l], LDW = LDWa[l];
      for (int n = 0; n < 32; n++) {
        const int grow = (n >> 3) * 256 + g * 8 + (n & 7);   // gate*SS + jglob
        const float* src = Wsrc[l] + (size_t)grow * K;
        unsigned short* dst = wlds + WOFFa[l] + n * LDW;
        for (int k = tid; k < K; k += 256) dst[k] = f2bf(src[k]);
      }
      if (tid < 32) biasl[l * 32 + tid] = bsrc[l][(tid >> 3) * 256 + g * 8 + (tid & 7)];
    }
    for (int i = tid; i < 8 * 128; i += 256) woutl[(i >> 7) * WSTR + (i & 127)] = Wout[i];
    if (tid < 8) boutl[tid] = bout[tid];
  }
  __syncthreads();

  f32x4 pc[4];                     // prevC (fp32, thread-private: 4 (row,j) per layer)
#pragma unroll
  for (int l = 0; l < 4; l++) pc[l] = zero_f4();
  unsigned phase = 0;

  const int wv = tid >> 6, lane = tid & 63, lm = lane & 15, quad = lane >> 4;
  const int m0 = wv * 32;          // wave's first batch row (2 M-tiles per wave)

  for (int t = 0; t < TT; t++) {
    auto do_layer = [&](auto Lc) {
      constexpr int L = decltype(Lc)::value;
      constexpr int K   = KLa[L];
      constexpr int NKT = K / 32;
      constexpr int DL  = DILa[L];
      constexpr int P   = PERa[L];
      constexpr int LDW = LDWa[L];
      const unsigned short* wl = wlds + WOFFa[L];
      const unsigned short* phb =
          (t >= 1) ? bufH[L] + (size_t)((t - 1) % P) * ROWS * HSW : nullptr;
      const unsigned short* dhb =
          (t >= DL) ? bufH[L] + (size_t)((t - DL) % P) * ROWS * HSW : phb;
      const unsigned short* ob = (L > 0) ? outb[L - 1] : nullptr;
      const float* xb = x + ((size_t)t * BBATCH + (size_t)c * ROWS) * INW;

      // ---- gates[128 x 32] = xh @ Wslice^T  (MFMA 16x16x32 bf16) ----
      f32x4 acc00 = zero_f4(), acc01 = zero_f4(), acc10 = zero_f4(), acc11 = zero_f4();
#pragma unroll
      for (int kt = 0; kt < NKT; kt++) {
        const int sty  = seg_type(L, kt * 32);    // folds at compile time
        const int sst  = seg_start(L, kt * 32);
        const int kloc = kt * 32 - sst + quad * 8;
        short8 a0, a1;
        if (sty == 0) {
          const float* p = xb + (size_t)(m0 + lm) * INW + kloc;
          a0 = ld8f(p);
          a1 = ld8f(p + 16 * INW);
        } else {
          const unsigned short* sb = (sty == 1) ? ob : ((sty == 2) ? phb : dhb);
          if (sb) {
            const unsigned short* p = sb + (size_t)(m0 + lm) * HSW + kloc;
            a0 = *(const short8*)p;
            a1 = *(const short8*)(p + 16 * HSW);
          } else {
            a0 = zero_s8();
            a1 = zero_s8();
          }
        }
        const short8 bf0 = *(const short8*)(wl + (size_t)lm * LDW + kt * 32 + quad * 8);
        const short8 bf1 = *(const short8*)(wl + (size_t)(16 + lm) * LDW + kt * 32 + quad * 8);
        acc00 = mfma16(a0, bf0, acc00);
        acc01 = mfma16(a0, bf1, acc01);
        acc10 = mfma16(a1, bf0, acc10);
        acc11 = mfma16(a1, bf1, acc11);
      }
      // C-layout: col = lane&15, row = quad*4 + reg  (m89-verified)
#pragma unroll
      for (int r = 0; r < 4; r++) {
        gates[(m0 + quad * 4 + r) * GSTRIDE + lm]           = acc00[r];
        gates[(m0 + quad * 4 + r) * GSTRIDE + 16 + lm]      = acc01[r];
        gates[(m0 + 16 + quad * 4 + r) * GSTRIDE + lm]      = acc10[r];
        gates[(m0 + 16 + quad * 4 + r) * GSTRIDE + 16 + lm] = acc11[r];
      }
      __syncthreads();

      // ---- cell elementwise: thread owns (row = tid&127, j0 = (tid>>7)*4 .. +3) ----
      {
        const int row = tid & 127, j0 = (tid >> 7) * 4;
        const f32x4 G0 = *(const f32x4*)&gates[row * GSTRIDE + 0 + j0];
        const f32x4 G1 = *(const f32x4*)&gates[row * GSTRIDE + 8 + j0];
        const f32x4 G2 = *(const f32x4*)&gates[row * GSTRIDE + 16 + j0];
        const f32x4 G3 = *(const f32x4*)&gates[row * GSTRIDE + 24 + j0];
        float* cs = bufC[L] + ((size_t)(t % DL) * ROWS + row) * 8 + j0;
        f32x4 dC = zero_f4();
        if (t >= DL) dC = *(const f32x4*)cs;    // C from t-dil
        const f32x4 pcv = pc[L];
        f32x4 nC, wh;
#pragma unroll
        for (int q = 0; q < 4; q++) {
          const float fg = sigm(G0[q] + biasl[L * 32 + 0  + j0 + q] + 1.0f);
          const float cd = tanh_(G1[q] + biasl[L * 32 + 8  + j0 + q]);
          const float al = sigm(G2[q] + biasl[L * 32 + 16 + j0 + q]);
          const float og = sigm(G3[q] + biasl[L * 32 + 24 + j0 + q]);
          const float wc = (t >= DL) ? (al * pcv[q] + (1.0f - al) * dC[q]) : pcv[q];
          const float nc = (t >= 1) ? (fg * wc + (1.0f - fg) * cd) : cd;
          nC[q] = nc;
          wh[q] = og * nc;
        }
        *(f32x4*)cs = nC;           // C ring slot t%dil (read at t+dil)
        pc[L] = nC;
        ushort4 wb;
        wb.x = f2bf(wh[0]); wb.y = f2bf(wh[1]); wb.z = f2bf(wh[2]); wb.w = f2bf(wh[3]);
        const int jg = g * 8 + j0;
        if (g < 16) {               // whole[:, :128] -> next-layer input
          *(ushort4*)(outb[L] + (size_t)row * OSW + jg) = wb;
        } else {                    // whole[:, 128:] -> h ring slot t%(dil+1)
          *(ushort4*)(bufH[L] + ((size_t)(t % P) * ROWS + row) * HSW + (jg - 128)) = wb;
        }
      }
      phase++;
      cluster_barrier(ctr, 32u * phase);
    };
    do_layer(IC<0>{});
    do_layer(IC<1>{});
    do_layer(IC<2>{});
    do_layer(IC<3>{});

    // ---- y = out3 @ Wout^T + bout; wave w -> row g*4+w, 8 lanes per (r,o) ----
    {
      const int o = (tid >> 3) & 7;
      const int s = tid & 7;
      const int r = g * 4 + (tid >> 6);
      const unsigned short* orow = outb[3] + (size_t)r * OSW;
      float part = 0.f;
#pragma unroll
      for (int i = 0; i < 16; i++) {
        const int k = s * 16 + i;
        part += bf2f(orow[k]) * woutl[o * WSTR + k];
      }
      part += __shfl_down(part, 4);
      part += __shfl_down(part, 2);
      part += __shfl_down(part, 1);
      if (s == 0)
        yout[((size_t)t * BBATCH + (size_t)c * ROWS + r) * NO + o] = part + boutl[o];
    }
  }
}

extern "C" void kernel_launch(void* const* d_in, const int* in_sizes, int n_in,
                              void* d_out, int out_size, void* d_ws, size_t ws_size,
                              hipStream_t stream) {
  const float* x    = (const float*)d_in[0];
  const float* W0   = (const float*)d_in[1];
  const float* b0   = (const float*)d_in[2];
  const float* W1   = (const float*)d_in[3];
  const float* b1   = (const float*)d_in[4];
  const float* W2   = (const float*)d_in[5];
  const float* b2   = (const float*)d_in[6];
  const float* W3   = (const float*)d_in[7];
  const float* b3   = (const float*)d_in[8];
  const float* Wout = (const float*)d_in[9];
  const float* bout = (const float*)d_in[10];
  float* out = (float*)d_out;
  char* ws = (char*)d_ws;

  if (ws_size < WS_NEED) {
    fprintf(stderr, "kernel_launch: ws_size %zu < needed %zu\n", ws_size, (size_t)WS_NEED);
    return;
  }

  // zero barrier counters (ws is poisoned 0xAA before every launch)
  hipMemsetAsync(d_ws, 0, 4096, stream);

  hipError_t e = hipFuncSetAttribute((const void*)rnn_stack_kernel,
                                     hipFuncAttributeMaxDynamicSharedMemorySize,
                                     LDS_BYTES);
  if (e != hipSuccess) fprintf(stderr, "hipFuncSetAttribute: %d\n", (int)e);

  rnn_stack_kernel<<<dim3(256), dim3(256), LDS_BYTES, stream>>>(
      x, W0, b0, W1, b1, W2, b2, W3, b3, Wout, bout, out, ws);
  e = hipGetLastError();
  if (e != hipSuccess) fprintf(stderr, "launch error: %d\n", (int)e);
}